// Round 4
// baseline (3932.332 us; speedup 1.0000x reference)
//
#include <hip/hip_runtime.h>

typedef unsigned short u16;
typedef unsigned int u32;
typedef __bf16 bf16x8 __attribute__((ext_vector_type(8)));
typedef float f32x4 __attribute__((ext_vector_type(4)));
typedef u32 u32x4 __attribute__((ext_vector_type(4)));

union U8 { u32x4 u; u16 us[8]; bf16x8 bf; };

static __device__ __forceinline__ float b2f(u16 h) {
  union { u32 i; float f; } c; c.i = ((u32)h) << 16; return c.f;
}
static __device__ __forceinline__ u16 f2b(float f) {
  union { float f; u32 i; } c; c.f = f;
  u32 x = c.i;
  return (u16)((x + 0x7fffu + ((x >> 16) & 1u)) >> 16);
}

// acc += A(LDS bf16, stride sa, row clamp)[tm:tm+16, 0:K] @ B(global FP32, ldb)[0:K, 0:16]
// gBc must already point at B[0, tn_global].
static __device__ __forceinline__ f32x4 tile16(const u16* As, int sa, int maxrow,
                                               const float* gBc, int ldb, int K,
                                               int tm, f32x4 acc) {
  int lane = threadIdx.x & 63;
  int quad = lane >> 4, col = lane & 15;
  int row = tm + col; if (row > maxrow) row = maxrow;   // clamped rows guarded at store
  const u16* ap = As + row * sa + quad * 8;
  const float* bp = gBc + (long)(quad * 8) * ldb + col;
  for (int kt = 0; kt < (K >> 5); ++kt) {
    U8 a; a.u = *(const u32x4*)(ap + kt * 32);   // 16B aligned LDS read
    U8 b;
#pragma unroll
    for (int j = 0; j < 8; ++j) b.us[j] = f2b(bp[(long)(kt * 32 + j) * ldb]);
    acc = __builtin_amdgcn_mfma_f32_16x16x32_bf16(a.bf, b.bf, acc, 0, 0, 0);
  }
  return acc;
}

// ---------- Kernel A: one block per window (62.7KB static LDS)
// LN1+shift -> per-2-head {QKV GEMM, attention, proj rank-64 partial} -> scatter + shortcut
__global__ __launch_bounds__(256) void attn_block(
    const float* __restrict__ x, const float* __restrict__ n1g, const float* __restrict__ n1b,
    const float* __restrict__ qkvw, const float* __restrict__ qkvb,
    const float* __restrict__ projw, const float* __restrict__ projb,
    const float* __restrict__ rpb, float* __restrict__ out) {
  __shared__ __align__(16) u16 xw_s[49 * 384];   // LN1'd window tokens
  __shared__ __align__(16) u16 hg_s[49 * 192];   // Q|K|V for 2 heads
  __shared__ __align__(16) u16 o_s[49 * 64];     // attention output for 2 heads
  int w = blockIdx.x;
  int bimg = w >> 4, wloc = w & 15, wh = wloc >> 2, ww = wloc & 3;
  int wave = threadIdx.x >> 6, lane = threadIdx.x & 63;
  int quad = lane >> 4, col = lane & 15;

  // --- LN1 with cyclic-shift gather: one wave per token
  for (int tok = wave; tok < 49; tok += 4) {
    int ih = tok / 7, iw = tok % 7;
    int hr = wh * 7 + ih + 3; if (hr >= 28) hr -= 28;   // roll(-3)
    int wr = ww * 7 + iw + 3; if (wr >= 28) wr -= 28;
    const float* p = x + (long)(bimg * 784 + hr * 28 + wr) * 384 + lane * 6;
    float v[6];
#pragma unroll
    for (int t = 0; t < 6; ++t) v[t] = p[t];
    float s = 0.f, ss = 0.f;
#pragma unroll
    for (int t = 0; t < 6; ++t) { s += v[t]; ss += v[t] * v[t]; }
    for (int m = 32; m; m >>= 1) { s += __shfl_xor(s, m); ss += __shfl_xor(ss, m); }
    float mean = s * (1.0f / 384.0f);
    float var  = ss * (1.0f / 384.0f) - mean * mean;
    float rs = rsqrtf(var + 1e-5f);
    u16* o = xw_s + tok * 384 + lane * 6;
#pragma unroll
    for (int t = 0; t < 6; ++t)
      o[t] = f2b((v[t] - mean) * rs * n1g[lane * 6 + t] + n1b[lane * 6 + t]);
  }
  __syncthreads();

  // proj partial accumulators: wave owns row-tile wave*16, all 24 col-tiles
  f32x4 accp[24];
#pragma unroll
  for (int i = 0; i < 24; ++i) accp[i] = f32x4{0.f, 0.f, 0.f, 0.f};

  for (int hg = 0; hg < 6; ++hg) {   // 2 heads per iteration
    // --- QKV GEMM for heads {2hg, 2hg+1}: 4 row-tiles x 12 col-tiles
    for (int t5 = wave; t5 < 48; t5 += 4) {
      int tm = (t5 & 3) * 16, ct = t5 >> 2;
      int gcol = (ct >> 2) * 384 + hg * 64 + (ct & 3) * 16;   // q/k/v section
      int lc = ct * 16;
      f32x4 acc = {0.f, 0.f, 0.f, 0.f};
      acc = tile16(xw_s, 384, 48, qkvw + gcol, 1152, 384, tm, acc);
      float bv = qkvb[gcol + col];
#pragma unroll
      for (int rr = 0; rr < 4; ++rr) {
        int row = tm + quad * 4 + rr;
        if (row < 49) hg_s[row * 192 + lc + col] = f2b(acc[rr] + bv);
      }
    }
    __syncthreads();

    // --- attention: threads 0..97 = (2 local heads) x (49 queries)
    {
      int t = threadIdx.x;
      if (t < 98) {
        int hl = t / 49, head = hg * 2 + hl;
        int i = t % 49;
        float q[32];
#pragma unroll
        for (int d = 0; d < 32; ++d)
          q[d] = b2f(hg_s[i * 192 + hl * 32 + d]) * 0.17677669529663689f;
        int ih = i / 7, iw = i % 7;
        int regi = ((wh < 3) ? 0 : ((ih < 4) ? 1 : 2)) * 3 + ((ww < 3) ? 0 : ((iw < 4) ? 1 : 2));
        float s[49];
        float mx = -1e30f;
#pragma unroll
        for (int jh = 0; jh < 7; ++jh) {
          int rh = (wh < 3) ? 0 : ((jh < 4) ? 1 : 2);
#pragma unroll
          for (int jw = 0; jw < 7; ++jw) {
            int j = jh * 7 + jw;
            const u16* kp = hg_s + j * 192 + 64 + hl * 32;
            float dot = 0.f;
#pragma unroll
            for (int d = 0; d < 32; ++d) dot += q[d] * b2f(kp[d]);
            int regj = rh * 3 + ((ww < 3) ? 0 : ((jw < 4) ? 1 : 2));
            int idx = (ih - jh + 6) * 13 + (iw - jw + 6);
            float sv = dot + rpb[idx * 12 + head];
            if (regi != regj) sv -= 100.0f;
            s[j] = sv;
            mx = fmaxf(mx, sv);
          }
        }
        float l = 0.f;
#pragma unroll
        for (int j = 0; j < 49; ++j) { s[j] = expf(s[j] - mx); l += s[j]; }
        float inv = 1.0f / l;
        float oacc[32];
#pragma unroll
        for (int d = 0; d < 32; ++d) oacc[d] = 0.f;
#pragma unroll
        for (int j = 0; j < 49; ++j) {
          float pj = s[j];
          const u16* vp = hg_s + j * 192 + 128 + hl * 32;
#pragma unroll
          for (int d = 0; d < 32; ++d) oacc[d] += pj * b2f(vp[d]);
        }
        u16* op = o_s + i * 64 + hl * 32;
#pragma unroll
        for (int d = 0; d < 32; ++d) op[d] = f2b(oacc[d] * inv);
      }
    }
    __syncthreads();

    // --- proj rank-64 partial: accp += O_hg[49x64] @ projw[hg*64:+64, :]
    for (int i = 0; i < 24; ++i) {
      accp[i] = tile16(o_s, 64, 48, projw + (long)(hg * 64) * 384 + i * 16, 384, 64,
                       wave * 16, accp[i]);
    }
    // no sync needed: next QKV writes hg_s only; its end-sync orders o_s reuse
  }

  // --- epilogue: scatter (reverse shift) + bias + shortcut, fp32
  for (int i = 0; i < 24; ++i) {
    int tn = i * 16;
    float bv = projb[tn + col];
#pragma unroll
    for (int rr = 0; rr < 4; ++rr) {
      int row = wave * 16 + quad * 4 + rr;
      if (row < 49) {
        int ih = row / 7, iw = row % 7;
        int ho = wh * 7 + ih + 3; if (ho >= 28) ho -= 28;   // roll(+3)
        int wo = ww * 7 + iw + 3; if (wo >= 28) wo -= 28;
        long dst = (long)(bimg * 784 + ho * 28 + wo) * 384 + tn + col;
        out[dst] = accp[i][rr] + bv + x[dst];
      }
    }
  }
}

// ---------- Kernel B: 32 rows/block. LN2 -> FC1+GELU (4 col-quarters) -> FC2 -> +residual
__global__ __launch_bounds__(256) void mlp_block(
    const float* __restrict__ n2g, const float* __restrict__ n2b,
    const float* __restrict__ fc1w, const float* __restrict__ fc1b,
    const float* __restrict__ fc2w, const float* __restrict__ fc2b,
    float* out) {
  __shared__ __align__(16) u16 a_s[32 * 384];
  __shared__ __align__(16) u16 mid_s[32 * 384];   // one 384-col quarter of mid
  long r0 = (long)blockIdx.x * 32;
  int wave = threadIdx.x >> 6, lane = threadIdx.x & 63;
  int quad = lane >> 4, col = lane & 15;

  // --- LN2 over x2 (fp32 in d_out)
  for (int tok = wave; tok < 32; tok += 4) {
    const float* p = out + (r0 + tok) * 384 + lane * 6;
    float v[6];
#pragma unroll
    for (int t = 0; t < 6; ++t) v[t] = p[t];
    float s = 0.f, ss = 0.f;
#pragma unroll
    for (int t = 0; t < 6; ++t) { s += v[t]; ss += v[t] * v[t]; }
    for (int m = 32; m; m >>= 1) { s += __shfl_xor(s, m); ss += __shfl_xor(ss, m); }
    float mean = s * (1.0f / 384.0f);
    float var  = ss * (1.0f / 384.0f) - mean * mean;
    float rs = rsqrtf(var + 1e-5f);
    u16* o = a_s + tok * 384 + lane * 6;
#pragma unroll
    for (int t = 0; t < 6; ++t)
      o[t] = f2b((v[t] - mean) * rs * n2g[lane * 6 + t] + n2b[lane * 6 + t]);
  }
  __syncthreads();

  // fc2 accumulators: 48 tiles (2m x 24n), 12 per wave, over 4 K-quarters
  f32x4 acc2[12];
#pragma unroll
  for (int i5 = 0; i5 < 12; ++i5) acc2[i5] = f32x4{0.f, 0.f, 0.f, 0.f};

  for (int qtr = 0; qtr < 4; ++qtr) {
    // --- FC1 quarter: mid cols [qtr*384, +384)
    for (int t5 = wave; t5 < 48; t5 += 4) {
      int tm = (t5 & 1) * 16, tn_l = (t5 >> 1) * 16;
      int tn_g = qtr * 384 + tn_l;
      f32x4 acc = {0.f, 0.f, 0.f, 0.f};
      acc = tile16(a_s, 384, 31, fc1w + tn_g, 1536, 384, tm, acc);
      float bv = fc1b[tn_g + col];
#pragma unroll
      for (int rr = 0; rr < 4; ++rr) {
        int row = tm + quad * 4 + rr;
        float v = acc[rr] + bv;
        float gl = 0.5f * v * (1.0f + erff(v * 0.70710678118654752f));
        mid_s[row * 384 + tn_l + col] = f2b(gl);
      }
    }
    __syncthreads();
    // --- FC2 partial over K-block [qtr*384, +384)
    for (int i5 = 0; i5 < 12; ++i5) {
      int t5 = wave + 4 * i5;
      int tm = (t5 & 1) * 16, tn = (t5 >> 1) * 16;
      acc2[i5] = tile16(mid_s, 384, 31, fc2w + (long)qtr * 384 * 384 + tn, 384, 384,
                        tm, acc2[i5]);
    }
    __syncthreads();   // mid_s reused next quarter
  }

  // --- epilogue: bias + residual, fp32
  for (int i5 = 0; i5 < 12; ++i5) {
    int t5 = wave + 4 * i5;
    int tm = (t5 & 1) * 16, tn = (t5 >> 1) * 16;
    float bv = fc2b[tn + col];
#pragma unroll
    for (int rr = 0; rr < 4; ++rr) {
      int row = tm + quad * 4 + rr;
      long idx = (r0 + row) * 384 + tn + col;
      out[idx] = acc2[i5][rr] + bv + out[idx];
    }
  }
}

extern "C" void kernel_launch(void* const* d_in, const int* in_sizes, int n_in,
                              void* d_out, int out_size, void* d_ws, size_t ws_size,
                              hipStream_t stream) {
  const float* x     = (const float*)d_in[0];
  const float* n1g   = (const float*)d_in[1];
  const float* n1b   = (const float*)d_in[2];
  const float* qkvw  = (const float*)d_in[3];
  const float* qkvb  = (const float*)d_in[4];
  const float* projw = (const float*)d_in[5];
  const float* projb = (const float*)d_in[6];
  const float* rpb   = (const float*)d_in[7];
  const float* n2g   = (const float*)d_in[8];
  const float* n2b   = (const float*)d_in[9];
  const float* fc1w  = (const float*)d_in[10];
  const float* fc1b  = (const float*)d_in[11];
  const float* fc2w  = (const float*)d_in[12];
  const float* fc2b  = (const float*)d_in[13];
  float* out = (float*)d_out;
  (void)d_ws; (void)ws_size;   // zero workspace usage

  // Kernel A: LN1 + shift + window + QKV + attention + proj + shortcut -> d_out (x2, fp32)
  attn_block<<<1024, 256, 0, stream>>>(x, n1g, n1b, qkvw, qkvb, projw, projb, rpb, out);
  // Kernel B: LN2 + FC1 + GELU + FC2 + residual -> d_out (final, fp32)
  mlp_block<<<1568, 256, 0, stream>>>(n2g, n2b, fc1w, fc1b, fc2w, fc2b, out);
}

// Round 5
// 2370.178 us; speedup vs baseline: 1.6591x; 1.6591x over previous
//
#include <hip/hip_runtime.h>

typedef unsigned short u16;
typedef unsigned int u32;
typedef __bf16 bf16x8 __attribute__((ext_vector_type(8)));
typedef float f32x4 __attribute__((ext_vector_type(4)));
typedef u32 u32x4 __attribute__((ext_vector_type(4)));

union U8 { u32x4 u; u16 us[8]; bf16x8 bf; };

static __device__ __forceinline__ float b2f(u16 h) {
  union { u32 i; float f; } c; c.i = ((u32)h) << 16; return c.f;
}
static __device__ __forceinline__ u16 f2b(float f) {
  union { float f; u32 i; } c; c.f = f;
  u32 x = c.i;
  return (u16)((x + 0x7fffu + ((x >> 16) & 1u)) >> 16);
}

// ---------- weight transpose+convert: W[K][N] fp32 -> WT[N][K] bf16
__global__ __launch_bounds__(256) void wtrans(const float* __restrict__ W, u16* __restrict__ WT,
                                              int K, int N) {
  __shared__ float t[32][33];
  int n0 = blockIdx.x * 32, k0 = blockIdx.y * 32;
  int tx = threadIdx.x, ty = threadIdx.y;   // 32 x 8
#pragma unroll
  for (int r = 0; r < 4; ++r)
    t[ty + 8 * r][tx] = W[(long)(k0 + ty + 8 * r) * N + n0 + tx];
  __syncthreads();
#pragma unroll
  for (int r = 0; r < 4; ++r)
    WT[(long)(n0 + ty + 8 * r) * K + k0 + tx] = f2b(t[tx][ty + 8 * r]);
}

// ---------- Kernel A: one block per window
// LN1+shift -> per-2-head {QKV(MFMA, W^T), attention, proj rank-64 partial} -> scatter+shortcut
__global__ __launch_bounds__(256) void attn_block(
    const float* __restrict__ x, const float* __restrict__ n1g, const float* __restrict__ n1b,
    const u16* __restrict__ qkvwT, const float* __restrict__ qkvb,
    const u16* __restrict__ projwT, const float* __restrict__ projb,
    const float* __restrict__ rpb, float* __restrict__ out) {
  __shared__ __align__(16) u16 xw_s[49 * 392];   // LN1'd tokens, padded stride
  __shared__ __align__(16) u16 hg_s[49 * 200];   // Q|K|V for 2 heads
  __shared__ __align__(16) u16 o_s[49 * 72];     // attention out for 2 heads
  int w = blockIdx.x;
  int bimg = w >> 4, wloc = w & 15, wh = wloc >> 2, ww = wloc & 3;
  int wave = threadIdx.x >> 6, lane = threadIdx.x & 63;
  int quad = lane >> 4, col = lane & 15;

  // --- LN1 with cyclic-shift gather
  for (int tok = wave; tok < 49; tok += 4) {
    int ih = tok / 7, iw = tok % 7;
    int hr = wh * 7 + ih + 3; if (hr >= 28) hr -= 28;
    int wr = ww * 7 + iw + 3; if (wr >= 28) wr -= 28;
    const float* p = x + (long)(bimg * 784 + hr * 28 + wr) * 384 + lane * 6;
    float v[6];
#pragma unroll
    for (int t = 0; t < 6; ++t) v[t] = p[t];
    float s = 0.f, ss = 0.f;
#pragma unroll
    for (int t = 0; t < 6; ++t) { s += v[t]; ss += v[t] * v[t]; }
    for (int m = 32; m; m >>= 1) { s += __shfl_xor(s, m); ss += __shfl_xor(ss, m); }
    float mean = s * (1.0f / 384.0f);
    float var  = ss * (1.0f / 384.0f) - mean * mean;
    float rs = rsqrtf(var + 1e-5f);
    u16* o = xw_s + tok * 392 + lane * 6;
#pragma unroll
    for (int t = 0; t < 6; ++t)
      o[t] = f2b((v[t] - mean) * rs * n1g[lane * 6 + t] + n1b[lane * 6 + t]);
  }
  __syncthreads();

  f32x4 accp[24];
#pragma unroll
  for (int i = 0; i < 24; ++i) accp[i] = f32x4{0.f, 0.f, 0.f, 0.f};

  int arow = wave * 16 + col; if (arow > 48) arow = 48;

  for (int hg = 0; hg < 6; ++hg) {
    // --- QKV for heads {2hg,2hg+1}: 3 sections (q,k,v) x wave-owned row tile, 16m x 64n
    for (int s = 0; s < 3; ++s) {
      int gbase = s * 384 + hg * 64;
      const u16* ap = xw_s + arow * 392 + quad * 8;
      f32x4 acc[4];
#pragma unroll
      for (int c = 0; c < 4; ++c) acc[c] = f32x4{0.f, 0.f, 0.f, 0.f};
      for (int kt = 0; kt < 12; ++kt) {
        U8 a; a.u = *(const u32x4*)(ap + kt * 32);
#pragma unroll
        for (int c = 0; c < 4; ++c) {
          U8 b; b.u = *(const u32x4*)(qkvwT + (long)(gbase + c * 16 + col) * 384 + kt * 32 + quad * 8);
          acc[c] = __builtin_amdgcn_mfma_f32_16x16x32_bf16(a.bf, b.bf, acc[c], 0, 0, 0);
        }
      }
#pragma unroll
      for (int c = 0; c < 4; ++c) {
        float bv = qkvb[gbase + c * 16 + col];
#pragma unroll
        for (int rr = 0; rr < 4; ++rr) {
          int row = wave * 16 + quad * 4 + rr;
          if (row < 49) hg_s[row * 200 + s * 64 + c * 16 + col] = f2b(acc[c][rr] + bv);
        }
      }
    }
    __syncthreads();

    // --- attention: all 4 waves; wave -> (local head, query half)
    {
      int hl = wave >> 1, head = hg * 2 + hl;
      int i = (wave & 1) * 25 + lane;
      if (lane < 25 && i < 49) {
        float q[32];
#pragma unroll
        for (int t = 0; t < 4; ++t) {
          U8 a; a.u = *(const u32x4*)(hg_s + i * 200 + hl * 32 + t * 8);
#pragma unroll
          for (int j = 0; j < 8; ++j) q[t * 8 + j] = b2f(a.us[j]) * 0.17677669529663689f;
        }
        int ih = i / 7, iw = i % 7;
        int regi = ((wh < 3) ? 0 : ((ih < 4) ? 1 : 2)) * 3 + ((ww < 3) ? 0 : ((iw < 4) ? 1 : 2));
        float s[49];
        float mx = -1e30f;
#pragma unroll
        for (int jh = 0; jh < 7; ++jh) {
          int rh = (wh < 3) ? 0 : ((jh < 4) ? 1 : 2);
#pragma unroll
          for (int jw = 0; jw < 7; ++jw) {
            int j = jh * 7 + jw;
            float dot = 0.f;
#pragma unroll
            for (int t = 0; t < 4; ++t) {
              U8 kv; kv.u = *(const u32x4*)(hg_s + j * 200 + 64 + hl * 32 + t * 8);
#pragma unroll
              for (int d = 0; d < 8; ++d) dot += q[t * 8 + d] * b2f(kv.us[d]);
            }
            int regj = rh * 3 + ((ww < 3) ? 0 : ((jw < 4) ? 1 : 2));
            int idx = (ih - jh + 6) * 13 + (iw - jw + 6);
            float sv = dot + rpb[idx * 12 + head];
            if (regi != regj) sv -= 100.0f;
            s[j] = sv;
            mx = fmaxf(mx, sv);
          }
        }
        float l = 0.f;
#pragma unroll
        for (int j = 0; j < 49; ++j) { s[j] = __expf(s[j] - mx); l += s[j]; }
        float inv = 1.0f / l;
        float oacc[32];
#pragma unroll
        for (int d = 0; d < 32; ++d) oacc[d] = 0.f;
#pragma unroll
        for (int j = 0; j < 49; ++j) {
          float pj = s[j];
#pragma unroll
          for (int t = 0; t < 4; ++t) {
            U8 vv; vv.u = *(const u32x4*)(hg_s + j * 200 + 128 + hl * 32 + t * 8);
#pragma unroll
            for (int d = 0; d < 8; ++d) oacc[t * 8 + d] += pj * b2f(vv.us[d]);
          }
        }
        u16* op = o_s + i * 72 + hl * 32;
#pragma unroll
        for (int d = 0; d < 32; ++d) op[d] = f2b(oacc[d] * inv);
      }
    }
    __syncthreads();

    // --- proj rank-64 partial: accp += O_hg[49x64] @ projw[hg*64:+64, :]
    const u16* ap2 = o_s + arow * 72 + quad * 8;
    for (int cg = 0; cg < 6; ++cg) {
#pragma unroll
      for (int kt = 0; kt < 2; ++kt) {
        U8 a; a.u = *(const u32x4*)(ap2 + kt * 32);
#pragma unroll
        for (int c = 0; c < 4; ++c) {
          U8 b; b.u = *(const u32x4*)(projwT + (long)(cg * 64 + c * 16 + col) * 384 + hg * 64 + kt * 32 + quad * 8);
          accp[cg * 4 + c] = __builtin_amdgcn_mfma_f32_16x16x32_bf16(a.bf, b.bf, accp[cg * 4 + c], 0, 0, 0);
        }
      }
    }
    // safe: next QKV writes hg_s (attention done pre-barrier); o_s rewritten only after next QKV barrier
  }

  // --- epilogue: scatter (reverse shift) + bias + shortcut
  for (int i = 0; i < 24; ++i) {
    int tn = (i >> 2) * 64 + (i & 3) * 16;
    float bv = projb[tn + col];
#pragma unroll
    for (int rr = 0; rr < 4; ++rr) {
      int row = wave * 16 + quad * 4 + rr;
      if (row < 49) {
        int ih = row / 7, iw = row % 7;
        int ho = wh * 7 + ih + 3; if (ho >= 28) ho -= 28;
        int wo = ww * 7 + iw + 3; if (wo >= 28) wo -= 28;
        long dst = (long)(bimg * 784 + ho * 28 + wo) * 384 + tn + col;
        out[dst] = accp[i][rr] + bv + x[dst];
      }
    }
  }
}

// ---------- Kernel B: 32 rows/block. LN2 -> FC1+GELU (4 quarters) -> FC2 -> +residual
__global__ __launch_bounds__(256) void mlp_block(
    const float* __restrict__ n2g, const float* __restrict__ n2b,
    const u16* __restrict__ fc1wT, const float* __restrict__ fc1b,
    const u16* __restrict__ fc2wT, const float* __restrict__ fc2b,
    float* out) {
  __shared__ __align__(16) u16 a_s[32 * 392];
  __shared__ __align__(16) u16 mid_s[32 * 392];
  long r0 = (long)blockIdx.x * 32;
  int wave = threadIdx.x >> 6, lane = threadIdx.x & 63;
  int quad = lane >> 4, col = lane & 15;

  // --- LN2
  for (int tok = wave; tok < 32; tok += 4) {
    const float* p = out + (r0 + tok) * 384 + lane * 6;
    float v[6];
#pragma unroll
    for (int t = 0; t < 6; ++t) v[t] = p[t];
    float s = 0.f, ss = 0.f;
#pragma unroll
    for (int t = 0; t < 6; ++t) { s += v[t]; ss += v[t] * v[t]; }
    for (int m = 32; m; m >>= 1) { s += __shfl_xor(s, m); ss += __shfl_xor(ss, m); }
    float mean = s * (1.0f / 384.0f);
    float var  = ss * (1.0f / 384.0f) - mean * mean;
    float rs = rsqrtf(var + 1e-5f);
    u16* o = a_s + tok * 392 + lane * 6;
#pragma unroll
    for (int t = 0; t < 6; ++t)
      o[t] = f2b((v[t] - mean) * rs * n2g[lane * 6 + t] + n2b[lane * 6 + t]);
  }
  __syncthreads();

  f32x4 acc2[12];
#pragma unroll
  for (int i = 0; i < 12; ++i) acc2[i] = f32x4{0.f, 0.f, 0.f, 0.f};
  int rt2 = wave & 1, nb = (wave >> 1) * 192;

  for (int qtr = 0; qtr < 4; ++qtr) {
    // --- FC1 quarter: 12 tasks (2 row-tiles x 6 col-groups), 3 rounds
    for (int r = 0; r < 3; ++r) {
      int id = wave + 4 * r;
      int rt = id & 1, cgl = id >> 1;
      int gbase = qtr * 384 + cgl * 64;
      const u16* ap = a_s + (rt * 16 + col) * 392 + quad * 8;
      f32x4 acc[4];
#pragma unroll
      for (int c = 0; c < 4; ++c) acc[c] = f32x4{0.f, 0.f, 0.f, 0.f};
      for (int kt = 0; kt < 12; ++kt) {
        U8 a; a.u = *(const u32x4*)(ap + kt * 32);
#pragma unroll
        for (int c = 0; c < 4; ++c) {
          U8 b; b.u = *(const u32x4*)(fc1wT + (long)(gbase + c * 16 + col) * 384 + kt * 32 + quad * 8);
          acc[c] = __builtin_amdgcn_mfma_f32_16x16x32_bf16(a.bf, b.bf, acc[c], 0, 0, 0);
        }
      }
#pragma unroll
      for (int c = 0; c < 4; ++c) {
        float bv = fc1b[gbase + c * 16 + col];
#pragma unroll
        for (int rr = 0; rr < 4; ++rr) {
          int row = rt * 16 + quad * 4 + rr;
          float v = acc[c][rr] + bv;
          float gl = 0.5f * v * (1.0f + erff(v * 0.70710678118654752f));
          mid_s[row * 392 + cgl * 64 + c * 16 + col] = f2b(gl);
        }
      }
    }
    __syncthreads();
    // --- FC2 partial: wave owns 16m x 192n (3 groups of 64)
    const u16* ap2 = mid_s + (rt2 * 16 + col) * 392 + quad * 8;
    for (int g = 0; g < 3; ++g) {
      for (int kt = 0; kt < 12; ++kt) {
        U8 a; a.u = *(const u32x4*)(ap2 + kt * 32);
#pragma unroll
        for (int c = 0; c < 4; ++c) {
          int n = nb + g * 64 + c * 16 + col;
          U8 b; b.u = *(const u32x4*)(fc2wT + (long)n * 1536 + qtr * 384 + kt * 32 + quad * 8);
          acc2[g * 4 + c] = __builtin_amdgcn_mfma_f32_16x16x32_bf16(a.bf, b.bf, acc2[g * 4 + c], 0, 0, 0);
        }
      }
    }
    __syncthreads();
  }

  // --- epilogue: bias + residual
#pragma unroll
  for (int g = 0; g < 3; ++g)
#pragma unroll
    for (int c = 0; c < 4; ++c) {
      int tn = nb + g * 64 + c * 16;
      float bv = fc2b[tn + col];
#pragma unroll
      for (int rr = 0; rr < 4; ++rr) {
        int row = rt2 * 16 + quad * 4 + rr;
        long idx = (r0 + row) * 384 + tn + col;
        out[idx] = acc2[g * 4 + c][rr] + bv + out[idx];
      }
    }
}

extern "C" void kernel_launch(void* const* d_in, const int* in_sizes, int n_in,
                              void* d_out, int out_size, void* d_ws, size_t ws_size,
                              hipStream_t stream) {
  const float* x     = (const float*)d_in[0];
  const float* n1g   = (const float*)d_in[1];
  const float* n1b   = (const float*)d_in[2];
  const float* qkvw  = (const float*)d_in[3];
  const float* qkvb  = (const float*)d_in[4];
  const float* projw = (const float*)d_in[5];
  const float* projb = (const float*)d_in[6];
  const float* rpb   = (const float*)d_in[7];
  const float* n2g   = (const float*)d_in[8];
  const float* n2b   = (const float*)d_in[9];
  const float* fc1w  = (const float*)d_in[10];
  const float* fc1b  = (const float*)d_in[11];
  const float* fc2w  = (const float*)d_in[12];
  const float* fc2b  = (const float*)d_in[13];
  float* out = (float*)d_out;

  // ws: bf16 W^T copies (3.54 MB total)
  u16* qkvwT = (u16*)d_ws;
  u16* projwT = qkvwT + 442368;
  u16* fc1wT  = projwT + 147456;
  u16* fc2wT  = fc1wT + 589824;

  wtrans<<<dim3(36, 12), dim3(32, 8), 0, stream>>>(qkvw, qkvwT, 384, 1152);
  wtrans<<<dim3(12, 12), dim3(32, 8), 0, stream>>>(projw, projwT, 384, 384);
  wtrans<<<dim3(48, 12), dim3(32, 8), 0, stream>>>(fc1w, fc1wT, 384, 1536);
  wtrans<<<dim3(12, 48), dim3(32, 8), 0, stream>>>(fc2w, fc2wT, 1536, 384);

  attn_block<<<1024, 256, 0, stream>>>(x, n1g, n1b, qkvwT, qkvb, projwT, projb, rpb, out);
  mlp_block<<<1568, 256, 0, stream>>>(n2g, n2b, fc1wT, fc1b, fc2wT, fc2b, out);
}

// Round 7
// 688.523 us; speedup vs baseline: 5.7113x; 3.4424x over previous
//
#include <hip/hip_runtime.h>

typedef unsigned short u16;
typedef unsigned int u32;
typedef __bf16 bf16x8 __attribute__((ext_vector_type(8)));
typedef float f32x4 __attribute__((ext_vector_type(4)));
typedef u32 u32x4 __attribute__((ext_vector_type(4)));

union U8 { u32x4 u; u16 us[8]; bf16x8 bf; };

static __device__ __forceinline__ float b2f(u16 h) {
  union { u32 i; float f; } c; c.i = ((u32)h) << 16; return c.f;
}
static __device__ __forceinline__ u16 f2b(float f) {
  union { float f; u32 i; } c; c.f = f;
  u32 x = c.i;
  return (u16)((x + 0x7fffu + ((x >> 16) & 1u)) >> 16);
}

// ---------- weight transpose+convert: W[K][N] fp32 -> WT[N][K] bf16
__global__ __launch_bounds__(256) void wtrans(const float* __restrict__ W, u16* __restrict__ WT,
                                              int K, int N) {
  __shared__ float t[32][33];
  int n0 = blockIdx.x * 32, k0 = blockIdx.y * 32;
  int tx = threadIdx.x, ty = threadIdx.y;   // 32 x 8
#pragma unroll
  for (int r = 0; r < 4; ++r)
    t[ty + 8 * r][tx] = W[(long)(k0 + ty + 8 * r) * N + n0 + tx];
  __syncthreads();
#pragma unroll
  for (int r = 0; r < 4; ++r)
    WT[(long)(n0 + ty + 8 * r) * K + k0 + tx] = f2b(t[tx][ty + 8 * r]);
}

// ---------- LayerNorm: MODE 0 = shift+window gather (LN1), MODE 1 = direct rows (LN2)
template<int MODE>
__global__ __launch_bounds__(256) void ln_kernel(const float* __restrict__ src,
                                                 const float* __restrict__ g,
                                                 const float* __restrict__ b,
                                                 u16* __restrict__ dst) {
  int tok = blockIdx.x * 4 + (threadIdx.x >> 6);   // destination (windowed) token
  int lane = threadIdx.x & 63;
  long srow;
  if (MODE == 0) {
    int wg = tok / 49, i = tok % 49;
    int bimg = wg >> 4, wloc = wg & 15;
    int wh = wloc >> 2, ww = wloc & 3;
    int ih = i / 7, iw = i % 7;
    int hr = wh * 7 + ih + 3; if (hr >= 28) hr -= 28;  // roll(-3)
    int wr = ww * 7 + iw + 3; if (wr >= 28) wr -= 28;
    srow = (long)(bimg * 784 + hr * 28 + wr) * 384;
  } else {
    srow = (long)tok * 384;
  }
  const float* p = src + srow + lane * 6;
  float v[6];
#pragma unroll
  for (int t = 0; t < 6; ++t) v[t] = p[t];
  float s = 0.f, ss = 0.f;
#pragma unroll
  for (int t = 0; t < 6; ++t) { s += v[t]; ss += v[t] * v[t]; }
  for (int m = 32; m; m >>= 1) { s += __shfl_xor(s, m); ss += __shfl_xor(ss, m); }
  float mean = s * (1.0f / 384.0f);
  float var  = ss * (1.0f / 384.0f) - mean * mean;
  float rs = rsqrtf(var + 1e-5f);
  u16* o = dst + (long)tok * 384 + lane * 6;
#pragma unroll
  for (int t = 0; t < 6; ++t)
    o[t] = f2b((v[t] - mean) * rs * g[lane * 6 + t] + b[lane * 6 + t]);
}

// ---------- big-tile GEMM: C[M][N] = A[M][K] @ BT[N][K]^T + bias, M%128==0, N%128==0, K%64==0
// EPI: 0 = bf16 store (qkv), 1 = bf16 store + GELU (fc1),
//      2 = fp32 scatter + x residual (proj), 3 = fp32 RMW residual (fc2)
template<int EPI>
__global__ __launch_bounds__(256) void gemm_big(
    const u16* __restrict__ A, const u16* __restrict__ BT,
    const float* __restrict__ bias, const float* __restrict__ xres,
    u16* __restrict__ Cb, float* __restrict__ Cf, int N, int K) {
  __shared__ __align__(16) u16 As[128 * 72];   // padded stride 72: conflict-free b128
  __shared__ __align__(16) u16 Bs[128 * 72];
  const int tid = threadIdx.x;
  const int wave = tid >> 6, lane = tid & 63, quad = lane >> 4, col = lane & 15;
  const long m0 = (long)blockIdx.x * 128;
  const int n0 = blockIdx.y * 128;
  const int rm = (wave & 1) * 64, cn = (wave >> 1) * 64;
  f32x4 acc[4][4];
#pragma unroll
  for (int i = 0; i < 4; ++i)
#pragma unroll
    for (int j = 0; j < 4; ++j) acc[i][j] = f32x4{0.f, 0.f, 0.f, 0.f};

  const int K64 = K >> 6;
  const int srow = tid >> 3, sch = tid & 7;   // 32 rows x 8 chunks per pass, 4 passes
  const u16* gA = A + (m0 + srow) * (long)K + sch * 8;
  const u16* gB = BT + ((long)(n0 + srow)) * K + sch * 8;

  u32x4 ra[4], rb[4];
#pragma unroll
  for (int c = 0; c < 4; ++c) {
    ra[c] = *(const u32x4*)(gA + (long)c * 32 * K);
    rb[c] = *(const u32x4*)(gB + (long)c * 32 * K);
  }

  for (int kt = 0; kt < K64; ++kt) {
    if (kt) __syncthreads();          // previous compute done before LDS overwrite
#pragma unroll
    for (int c = 0; c < 4; ++c) {
      *(u32x4*)&As[(srow + 32 * c) * 72 + sch * 8] = ra[c];
      *(u32x4*)&Bs[(srow + 32 * c) * 72 + sch * 8] = rb[c];
    }
    __syncthreads();
    if (kt + 1 < K64) {               // prefetch next tile into regs (overlaps MFMA)
#pragma unroll
      for (int c = 0; c < 4; ++c) {
        ra[c] = *(const u32x4*)(gA + (long)c * 32 * K + (kt + 1) * 64);
        rb[c] = *(const u32x4*)(gB + (long)c * 32 * K + (kt + 1) * 64);
      }
    }
#pragma unroll
    for (int kk = 0; kk < 2; ++kk) {
      U8 af[4], bfr[4];
#pragma unroll
      for (int i = 0; i < 4; ++i)
        af[i].u = *(const u32x4*)&As[(rm + i * 16 + col) * 72 + kk * 32 + quad * 8];
#pragma unroll
      for (int j = 0; j < 4; ++j)
        bfr[j].u = *(const u32x4*)&Bs[(cn + j * 16 + col) * 72 + kk * 32 + quad * 8];
#pragma unroll
      for (int i = 0; i < 4; ++i)
#pragma unroll
        for (int j = 0; j < 4; ++j)
          acc[i][j] = __builtin_amdgcn_mfma_f32_16x16x32_bf16(af[i].bf, bfr[j].bf, acc[i][j], 0, 0, 0);
    }
  }

  // ---- epilogue
#pragma unroll
  for (int j = 0; j < 4; ++j) {
    int n = n0 + cn + j * 16 + col;
    float bv = bias[n];
#pragma unroll
    for (int i = 0; i < 4; ++i) {
#pragma unroll
      for (int rr = 0; rr < 4; ++rr) {
        int row = (int)m0 + rm + i * 16 + quad * 4 + rr;
        float v = acc[i][j][rr] + bv;
        if (EPI == 0) {
          Cb[(long)row * N + n] = f2b(v);
        } else if (EPI == 1) {
          float gl = 0.5f * v * (1.0f + erff(v * 0.70710678118654752f));
          Cb[(long)row * N + n] = f2b(gl);
        } else if (EPI == 2) {
          int wg = row / 49, i49 = row - wg * 49;
          int bimg = wg >> 4, wloc = wg & 15;
          int wh = wloc >> 2, ww = wloc & 3;
          int ih = i49 / 7, iw = i49 - (i49 / 7) * 7;
          int ho = wh * 7 + ih + 3; if (ho >= 28) ho -= 28;   // roll(+3) back
          int wo = ww * 7 + iw + 3; if (wo >= 28) wo -= 28;
          long dst = (long)(bimg * 784 + ho * 28 + wo) * 384 + n;
          Cf[dst] = v + xres[dst];
        } else {
          long idx = (long)row * 384 + n;
          Cf[idx] = v + Cf[idx];
        }
      }
    }
  }
}

// ---------- attention: block = (window, 4 heads); K,V staged as f32 in LDS
__global__ __launch_bounds__(256) void attn_kernel(const u16* __restrict__ qkv,
                                                   const float* __restrict__ rpb,
                                                   u16* __restrict__ obuf) {
  __shared__ __align__(16) float ks[4 * 49 * 32];
  __shared__ __align__(16) float vs[4 * 49 * 32];
  int w = blockIdx.x, h0 = blockIdx.y * 4;
  int wloc = w & 15, wh = wloc >> 2, ww = wloc & 3;

  for (int c = threadIdx.x; c < 1568; c += 256) {
    int kv = (c >= 784) ? 1 : 0;
    int c2 = c - kv * 784;
    int h = c2 / 196, r = c2 - h * 196, j = r >> 2, cc = r & 3;
    U8 t; t.u = *(const u32x4*)(qkv + ((long)w * 49 + j) * 1152 + 384 + kv * 384 + (h0 + h) * 32 + cc * 8);
    float* d = (kv ? vs : ks) + (h * 49 + j) * 32 + cc * 8;
#pragma unroll
    for (int e = 0; e < 8; ++e) d[e] = b2f(t.us[e]);
  }
  __syncthreads();

  int hl = threadIdx.x >> 6, lane = threadIdx.x & 63;
  int head = h0 + hl;
  int i = lane;
  if (lane < 49) {
    const u16* qp = qkv + ((long)w * 49 + i) * 1152 + head * 32;
    float q[32];
#pragma unroll
    for (int t = 0; t < 4; ++t) {
      U8 a; a.u = *(const u32x4*)(qp + t * 8);
#pragma unroll
      for (int e = 0; e < 8; ++e) q[t * 8 + e] = b2f(a.us[e]) * 0.17677669529663689f;
    }
    int ih = i / 7, iw = i % 7;
    int regi = ((wh < 3) ? 0 : ((ih < 4) ? 1 : 2)) * 3 + ((ww < 3) ? 0 : ((iw < 4) ? 1 : 2));
    const float* kbase = ks + hl * 49 * 32;
    const float* vbase = vs + hl * 49 * 32;
    float s[49];
    float mx = -1e30f;
#pragma unroll
    for (int jh = 0; jh < 7; ++jh) {
      int rh = (wh < 3) ? 0 : ((jh < 4) ? 1 : 2);
#pragma unroll
      for (int jw = 0; jw < 7; ++jw) {
        int j = jh * 7 + jw;
        const float* kp = kbase + j * 32;
        float dot = 0.f;
#pragma unroll
        for (int d = 0; d < 32; ++d) dot += q[d] * kp[d];
        int regj = rh * 3 + ((ww < 3) ? 0 : ((jw < 4) ? 1 : 2));
        int idx = (ih - jh + 6) * 13 + (iw - jw + 6);
        float sv = dot + rpb[idx * 12 + head];
        if (regi != regj) sv -= 100.0f;
        s[j] = sv;
        mx = fmaxf(mx, sv);
      }
    }
    float l = 0.f;
#pragma unroll
    for (int j = 0; j < 49; ++j) { s[j] = __expf(s[j] - mx); l += s[j]; }
    float inv = 1.0f / l;
    float oacc[32];
#pragma unroll
    for (int d = 0; d < 32; ++d) oacc[d] = 0.f;
#pragma unroll
    for (int j = 0; j < 49; ++j) {
      float pj = s[j];
      const float* vp = vbase + j * 32;
#pragma unroll
      for (int d = 0; d < 32; ++d) oacc[d] += pj * vp[d];
    }
    u16* op = obuf + ((long)w * 49 + i) * 384 + head * 32;
#pragma unroll
    for (int t = 0; t < 4; ++t) {
      U8 o;
#pragma unroll
      for (int e = 0; e < 8; ++e) o.us[e] = f2b(oacc[t * 8 + e] * inv);
      *(u32x4*)(op + t * 8) = o.u;
    }
  }
}

extern "C" void kernel_launch(void* const* d_in, const int* in_sizes, int n_in,
                              void* d_out, int out_size, void* d_ws, size_t ws_size,
                              hipStream_t stream) {
  const float* x     = (const float*)d_in[0];
  const float* n1g   = (const float*)d_in[1];
  const float* n1b   = (const float*)d_in[2];
  const float* qkvw  = (const float*)d_in[3];
  const float* qkvb  = (const float*)d_in[4];
  const float* projw = (const float*)d_in[5];
  const float* projb = (const float*)d_in[6];
  const float* rpb   = (const float*)d_in[7];
  const float* n2g   = (const float*)d_in[8];
  const float* n2b   = (const float*)d_in[9];
  const float* fc1w  = (const float*)d_in[10];
  const float* fc1b  = (const float*)d_in[11];
  const float* fc2w  = (const float*)d_in[12];
  const float* fc2b  = (const float*)d_in[13];
  float* out = (float*)d_out;

  // ws layout (u16 units): weights 1.77M | region A 19.27M (xw -> obuf -> abuf) | region B 77.07M (qkv -> mid)
  u16* qkvwT  = (u16*)d_ws;                 // 442368
  u16* projwT = qkvwT + 442368;             // 147456
  u16* fc1wT  = projwT + 147456;            // 589824
  u16* fc2wT  = fc1wT + 589824;             // 589824  (ends 1769472)
  u16* wsA    = fc2wT + 589824;             // 19267584 (ends 21037056)
  u16* wsB    = wsA + 19267584;             // 77070336 (ends 98107392 = 196.2 MB)
  u16* xw   = wsA;        // LN1 out [50176][384]
  u16* obuf = wsA;        // attention out (xw dead after qkv GEMM)
  u16* abuf = wsA;        // LN2 out (obuf dead after proj)
  u16* qkvB = wsB;        // [50176][1152]
  u16* midB = wsB;        // [50176][1536] (qkv dead after attention)

  // weights -> bf16 W^T
  wtrans<<<dim3(36, 12), dim3(32, 8), 0, stream>>>(qkvw, qkvwT, 384, 1152);
  wtrans<<<dim3(12, 12), dim3(32, 8), 0, stream>>>(projw, projwT, 384, 384);
  wtrans<<<dim3(48, 12), dim3(32, 8), 0, stream>>>(fc1w, fc1wT, 384, 1536);
  wtrans<<<dim3(12, 48), dim3(32, 8), 0, stream>>>(fc2w, fc2wT, 1536, 384);

  // 1. LN1 + shift + window -> xw
  ln_kernel<0><<<12544, 256, 0, stream>>>(x, n1g, n1b, xw);
  // 2. QKV GEMM -> qkvB
  gemm_big<0><<<dim3(392, 9), 256, 0, stream>>>(xw, qkvwT, qkvb, nullptr, qkvB, nullptr, 1152, 384);
  // 3. windowed attention -> obuf
  attn_kernel<<<dim3(1024, 3), 256, 0, stream>>>(qkvB, rpb, obuf);
  // 4. proj GEMM + reverse-shift scatter + shortcut -> d_out (x2, fp32)
  gemm_big<2><<<dim3(392, 3), 256, 0, stream>>>(obuf, projwT, projb, x, nullptr, out, 384, 384);
  // 5. LN2 -> abuf
  ln_kernel<1><<<12544, 256, 0, stream>>>(out, n2g, n2b, abuf);
  // 6. FC1 + GELU -> midB
  gemm_big<1><<<dim3(392, 12), 256, 0, stream>>>(abuf, fc1wT, fc1b, nullptr, midB, nullptr, 1536, 384);
  // 7. FC2 + residual RMW -> d_out
  gemm_big<3><<<dim3(392, 3), 256, 0, stream>>>(midB, fc2wT, fc2b, nullptr, nullptr, out, 384, 1536);
}